// Round 20
// baseline (150.488 us; speedup 1.0000x reference)
//
#include <hip/hip_runtime.h>
#include <hip/hip_bf16.h>
#include <cstdint>

// ---------------------------------------------------------------------------
// Binarized CNN. Verified numerics (R5-R19 passed bit-exact):
//  - binarize(x) == sign(x) exactly; layers 2-4 are exact small-int math in
//    any order -> any packing / instruction choice is safe.
//  - conv1: each accumulator chain MUST sum in (ky,kx,ic)-ascending order
//    (Eigen/XLA-CPU im2col). Chains independent; fma == mul+add (w in +-1/0).
//    DO NOT reorder WITHIN a chain. Pad value 1.0.
//  - k2/k3: MFMA i32_32x32x32_i8 per-tap GEMM, weights-as-A epilogue (R18).
//  - k4: dot4 2x2 (R12). k1 acc: oc-paired pk_fma (R13).
//  - R20: k1 computes 2 pool cells/thread. Window = 6 cols 4tx-1..4tx+4
//    loaded as ONE aligned float4 + 2 scalars (was 4 strided loads/cell);
//    3 non-overlapping pairs, cells share the middle pair. Same chain
//    order & broadcast parity per cell -> bit-exact. uint2 stores.
// ---------------------------------------------------------------------------

typedef __attribute__((ext_vector_type(2)))  float f32x2;
typedef __attribute__((ext_vector_type(4)))  int int4v;
typedef __attribute__((ext_vector_type(16))) int int16v;

#define WOFF_W2M 0          // int[9*64*4] = 9216 B (MFMA frag table L2)
#define WOFF_W3M 10240      // int[9*64*4] = 9216 B (MFMA frag table L3)
#define WOFF_W4P 20480      // int[2*8*9]  =  576 B (dot4 packs L4)
#define WOFF_W1D 28672      // f32x2[4*32] = 1024 B (padded {w2o,w2o+1} pairs)
#define WEIGHTS_BYTES 32768

#define A1_PB (2*256*256*4)     // bytes per batch (packed u32, 4 ch/dword)
#define A2_PB (4*254*254*4)
#define A3_PB (8*252*252*4)

__device__ __forceinline__ int dot4(int a, int b, int c) {
#if __has_builtin(__builtin_amdgcn_sdot4)
    return __builtin_amdgcn_sdot4(a, b, c, false);
#else
    int s = c;
#pragma unroll
    for (int j = 0; j < 4; ++j) {
        int av = (a << (24 - 8 * j)) >> 24;
        int bv = (b << (24 - 8 * j)) >> 24;
        s += av * bv;
    }
    return s;
#endif
}

__device__ __forceinline__ int fsign(float w) {
    return (w > 0.f) ? 1 : ((w < 0.f) ? -1 : 0);
}

// acc.lo += w.lo * v.lo ; acc.hi += w.hi * v.lo   (broadcast LOW of src1)
__device__ __forceinline__ void pkfma_lo(f32x2& acc, f32x2 w, f32x2 v) {
    asm("v_pk_fma_f32 %0, %1, %2, %0 op_sel:[0,0,0] op_sel_hi:[1,0,1]"
        : "+v"(acc) : "s"(w), "v"(v));
}
// acc.lo += w.lo * v.hi ; acc.hi += w.hi * v.hi   (broadcast HIGH of src1)
__device__ __forceinline__ void pkfma_hi(f32x2& acc, f32x2 w, f32x2 v) {
    asm("v_pk_fma_f32 %0, %1, %2, %0 op_sel:[0,1,0] op_sel_hi:[1,1,1]"
        : "+v"(acc) : "s"(w), "v"(v));
}

// ---- weight prep: 3 blocks (one per table group) -------------------------
__global__ __launch_bounds__(256) void kprep(const float* __restrict__ w1,
                                             const float* __restrict__ w2,
                                             const float* __restrict__ w3,
                                             const float* __restrict__ w4,
                                             int* __restrict__ w2m,
                                             int* __restrict__ w3m,
                                             int* __restrict__ w4p,
                                             f32x2* __restrict__ w1d) {
    int tid = threadIdx.x;
    int b = blockIdx.x;
    if (b == 0) {
        for (int idx = tid; idx < 576; idx += 256) {
            int t = idx / 64, l = idx % 64;
            int oc = l & 31, icb = (l >> 5) * 16;
            int wd[4] = {0, 0, 0, 0};
            for (int j = 0; j < 16; ++j) {
                int ic = icb + j;
                int s = (oc < 16 && ic < 8) ? fsign(w2[(oc * 8 + ic) * 9 + t]) : 0;
                wd[j >> 2] |= (s & 0xff) << (8 * (j & 3));
            }
            w2m[idx * 4 + 0] = wd[0]; w2m[idx * 4 + 1] = wd[1];
            w2m[idx * 4 + 2] = wd[2]; w2m[idx * 4 + 3] = wd[3];
        }
    } else if (b == 1) {
        for (int idx = tid; idx < 576; idx += 256) {
            int t = idx / 64, l = idx % 64;
            int oc = l & 31, icb = (l >> 5) * 16;
            int wd[4] = {0, 0, 0, 0};
            for (int j = 0; j < 16; ++j) {
                int ic = icb + j;
                int s = (ic < 16) ? fsign(w3[(oc * 16 + ic) * 9 + t]) : 0;
                wd[j >> 2] |= (s & 0xff) << (8 * (j & 3));
            }
            w3m[idx * 4 + 0] = wd[0]; w3m[idx * 4 + 1] = wd[1];
            w3m[idx * 4 + 2] = wd[2]; w3m[idx * 4 + 3] = wd[3];
        }
    } else {
        for (int idx = tid; idx < 2 * 8 * 9; idx += 256) {
            int k = idx % 9, icg = (idx / 9) % 8, oc = idx / 72;
            int pack = 0;
#pragma unroll
            for (int j = 0; j < 4; ++j)
                pack |= (fsign(w4[(oc * 32 + icg * 4 + j) * 9 + k]) & 0xff) << (8 * j);
            w4p[idx] = pack;
        }
        // padded table: w1d[op*32 + t] (t<27), 256B-aligned per op block
        for (int i = tid; i < 128; i += 256) {
            int op = i / 32, t = i % 32;
            f32x2 pr = {0.f, 0.f};
            if (t < 27) {
                float wa = w1[(2 * op) * 27 + t];
                float wbv = w1[(2 * op + 1) * 27 + t];
                pr[0] = (wa > 0.f) ? 1.f : ((wa < 0.f) ? -1.f : 0.f);
                pr[1] = (wbv > 0.f) ? 1.f : ((wbv < 0.f) ? -1.f : 0.f);
            }
            w1d[i] = pr;
        }
    }
}

// ---- layer 1: pad(1)+conv(3->8)+hardtanh+maxpool2+sign, packed out -------
// R20: 2 pool cells/thread. Window cols 4tx-1..4tx+4 as 3 pairs
// {-1,0},{1,2},{3,4}; cell A uses pairs 0,1 (cols 0..3), cell B pairs 1,2
// (cols 2..5). Chains strict (ky,kx,ic)-ascending per contract (verified).
__global__ __launch_bounds__(128, 4) void k1(const float* __restrict__ x,
                                             const f32x2* __restrict__ w1d,
                                             uint32_t* __restrict__ a1, int n0) {
    int tx = threadIdx.x;   // 0..127
    int oy = blockIdx.y;    // 0..255
    int ln = blockIdx.z;
    const float* xn = x + (size_t)(n0 + ln) * 3 * 512 * 512;

    int iy0 = 2 * oy - 1;
    int xb  = 4 * tx;        // window cols xb-1 .. xb+4

    f32x2 P[3][4][3];        // [ic][r][pair]

    if (oy > 0 && oy < 255 && tx > 0 && tx < 127) {
#pragma unroll
        for (int ic = 0; ic < 3; ++ic) {
            const float* xc = xn + (size_t)ic * 512 * 512;
#pragma unroll
            for (int r = 0; r < 4; ++r) {
                const float* rp = xc + (size_t)(iy0 + r) * 512 + xb;
                float  lft = rp[-1];
                float4 m   = *(const float4*)rp;    // cols xb..xb+3, 16B aligned
                float  rgt = rp[4];
                P[ic][r][0] = (f32x2){lft, m.x};
                P[ic][r][1] = (f32x2){m.y, m.z};
                P[ic][r][2] = (f32x2){m.w, rgt};
            }
        }
    } else {
        for (int ic = 0; ic < 3; ++ic) {
            const float* xc = xn + (size_t)ic * 512 * 512;
#pragma unroll
            for (int r = 0; r < 4; ++r) {
                int iy = iy0 + r;
                bool yok = ((unsigned)iy < 512u);
                float t[6];
#pragma unroll
                for (int c = 0; c < 6; ++c) {
                    int ix = xb - 1 + c;
                    t[c] = (yok && ((unsigned)ix < 512u))
                               ? xc[(size_t)iy * 512 + ix] : 1.0f;
                }
                P[ic][r][0] = (f32x2){t[0], t[1]};
                P[ic][r][1] = (f32x2){t[2], t[3]};
                P[ic][r][2] = (f32x2){t[4], t[5]};
            }
        }
    }

#define PKTAP(ACC, ROW, COL)                                         \
    do {                                                             \
        if (((COL) & 1) == 0) pkfma_lo(ACC, ww, P[ic][ROW][(COL) >> 1]); \
        else                  pkfma_hi(ACC, ww, P[ic][ROW][(COL) >> 1]); \
    } while (0)

    uint64_t dallA = 0, dallB = 0;
#pragma unroll 1
    for (int op = 0; op < 4; ++op) {
        const f32x2* wb = w1d + op * 32;
        f32x2 wop[27];
#pragma unroll
        for (int t = 0; t < 27; ++t) wop[t] = wb[t];

        f32x2 aA00 = {0.f, 0.f}, aA01 = {0.f, 0.f};
        f32x2 aA10 = {0.f, 0.f}, aA11 = {0.f, 0.f};
        f32x2 aB00 = {0.f, 0.f}, aB01 = {0.f, 0.f};
        f32x2 aB10 = {0.f, 0.f}, aB11 = {0.f, 0.f};
#pragma unroll
        for (int ky = 0; ky < 3; ++ky) {
#pragma unroll
            for (int kx = 0; kx < 3; ++kx) {
#pragma unroll
                for (int ic = 0; ic < 3; ++ic) {
                    f32x2 ww = wop[ic * 9 + ky * 3 + kx];
                    PKTAP(aA00, ky + 0, kx + 0);
                    PKTAP(aA01, ky + 0, kx + 1);
                    PKTAP(aA10, ky + 1, kx + 0);
                    PKTAP(aA11, ky + 1, kx + 1);
                    PKTAP(aB00, ky + 0, kx + 2);
                    PKTAP(aB01, ky + 0, kx + 3);
                    PKTAP(aB10, ky + 1, kx + 2);
                    PKTAP(aB11, ky + 1, kx + 3);
                }
            }
        }
        float mA0 = fmaxf(fmaxf(aA00[0], aA01[0]), fmaxf(aA10[0], aA11[0]));
        float mA1 = fmaxf(fmaxf(aA00[1], aA01[1]), fmaxf(aA10[1], aA11[1]));
        float mB0 = fmaxf(fmaxf(aB00[0], aB01[0]), fmaxf(aB10[0], aB11[0]));
        float mB1 = fmaxf(fmaxf(aB00[1], aB01[1]), fmaxf(aB10[1], aB11[1]));
        int sA0 = (mA0 > 0.f) ? 1 : ((mA0 < 0.f) ? -1 : 0);
        int sA1 = (mA1 > 0.f) ? 1 : ((mA1 < 0.f) ? -1 : 0);
        int sB0 = (mB0 > 0.f) ? 1 : ((mB0 < 0.f) ? -1 : 0);
        int sB1 = (mB1 > 0.f) ? 1 : ((mB1 < 0.f) ? -1 : 0);
        dallA |= (uint64_t)(uint32_t)(sA0 & 0xff) << (8 * (2 * op));
        dallA |= (uint64_t)(uint32_t)(sA1 & 0xff) << (8 * (2 * op + 1));
        dallB |= (uint64_t)(uint32_t)(sB0 & 0xff) << (8 * (2 * op));
        dallB |= (uint64_t)(uint32_t)(sB1 & 0xff) << (8 * (2 * op + 1));
    }
#undef PKTAP

    size_t base = (((size_t)ln * 2) * 256 + oy) * 256 + 2 * tx;
    uint2 v0, v1;
    v0.x = (uint32_t)dallA;         v0.y = (uint32_t)dallB;
    v1.x = (uint32_t)(dallA >> 32); v1.y = (uint32_t)(dallB >> 32);
    *(uint2*)(a1 + base)             = v0;
    *(uint2*)(a1 + base + 256 * 256) = v1;
}

// ---- layers 2/3: ternary conv via MFMA i32_32x32x32_i8 -------------------
// R18: operands swapped (weights=A, acts=B) -> C[row=oc, col=px]; in-register
// epilogue, direct global stores. R16: 8 rows/block, 10 staged rows.
template<int ICG, int INW, int OUTW, int OCGO>
__global__ __launch_bounds__(256) void kconv(const uint32_t* __restrict__ ain,
                                             const int* __restrict__ wm,
                                             uint32_t* __restrict__ aout) {
    __shared__ uint32_t stb[10][36][4];    // [row][x][icg], rows y0..y0+9
    constexpr int LG = (ICG == 2) ? 1 : 2;
    int w    = threadIdx.x >> 6;
    int lane = threadIdx.x & 63;
    int x0 = blockIdx.x * 32;
    int y0 = blockIdx.y * 8;
    int ln = blockIdx.z;

    const int4v* wmv = (const int4v*)wm;
    int4v bfr[9];
#pragma unroll
    for (int t = 0; t < 9; ++t) bfr[t] = wmv[t * 64 + lane];

    const uint32_t* abase = ain + (size_t)ln * ICG * INW * INW;
    for (int idx = threadIdx.x; idx < 10 * 36 * ICG; idx += 256) {
        int icg = idx & (ICG - 1);
        int r2 = idx >> LG;
        int xx = r2 % 36, row = r2 / 36;
        int gy = y0 + row, gx = x0 + xx;
        uint32_t val = 0;
        if (xx < 34 && gx < INW && gy < INW)
            val = abase[((size_t)icg * INW + gy) * INW + gx];
        stb[row][xx][icg] = val;
    }
    __syncthreads();

    int xl = lane & 31;
    int h  = lane >> 5;

#pragma unroll
    for (int ry = 0; ry < 2; ++ry) {
        int yy = y0 + 2 * w + ry;
        int16v acc = {};
#pragma unroll
        for (int ky = 0; ky < 3; ++ky) {
#pragma unroll
            for (int kx = 0; kx < 3; ++kx) {
                int4v a = *(const int4v*)&stb[2 * w + ry + ky][xl + kx][0];
                acc = __builtin_amdgcn_mfma_i32_32x32x32_i8(bfr[ky * 3 + kx], a, acc, 0, 0, 0);
            }
        }
        bool ok = (yy < OUTW) && (x0 + xl < OUTW);
#pragma unroll
        for (int g = 0; g < 4; ++g) {
            int ocg = 2 * g + h;              // oc = 8g + 4h + j, byte j
            if (ocg < OCGO && ok) {
                uint32_t dw = 0;
#pragma unroll
                for (int j = 0; j < 4; ++j) {
                    int v = min(max(acc[4 * g + j], -1), 1);
                    dw |= (uint32_t)(v & 0xff) << (8 * j);
                }
                aout[(((size_t)ln * OCGO + ocg) * OUTW + yy) * OUTW + x0 + xl] = dw;
            }
        }
    }
}

// ---- layer 4: conv(32->2) ternary, dot4, 2x2 outputs/thread, f32 out -----
__global__ __launch_bounds__(128) void k4(const uint32_t* __restrict__ a3,
                                          const int* __restrict__ w4p,
                                          float* __restrict__ out, int n0) {
    int ox = threadIdx.x; if (ox >= 125) return;
    int oy0 = blockIdx.y * 2;
    int ln = blockIdx.z;

    int acc[2][2][2] = {};
#pragma unroll
    for (int icg = 0; icg < 8; ++icg) {
        uint32_t r[4][4];
        const uint32_t* base = a3 + (((size_t)ln * 8 + icg) * 252 + oy0) * 252 + 2 * ox;
#pragma unroll
        for (int j = 0; j < 4; ++j) {
            uint2 lo = *(const uint2*)(base + (size_t)j * 252);
            uint2 hi = *(const uint2*)(base + (size_t)j * 252 + 2);
            r[j][0] = lo.x; r[j][1] = lo.y; r[j][2] = hi.x; r[j][3] = hi.y;
        }
#pragma unroll
        for (int o = 0; o < 2; ++o) {
            const int* wb = w4p + ((o * 8 + icg) * 9);
#pragma unroll
            for (int ky = 0; ky < 3; ++ky) {
#pragma unroll
                for (int p = 0; p < 2; ++p) {
#pragma unroll
                    for (int q = 0; q < 2; ++q) {
                        acc[p][q][o] = dot4((int)r[p + ky][q + 0], wb[ky * 3 + 0], acc[p][q][o]);
                        acc[p][q][o] = dot4((int)r[p + ky][q + 1], wb[ky * 3 + 1], acc[p][q][o]);
                        acc[p][q][o] = dot4((int)r[p + ky][q + 2], wb[ky * 3 + 2], acc[p][q][o]);
                    }
                }
            }
        }
    }
    size_t gn = (size_t)(n0 + ln);
#pragma unroll
    for (int o = 0; o < 2; ++o)
#pragma unroll
        for (int p = 0; p < 2; ++p) {
            float2 w;
            w.x = fminf(fmaxf((float)acc[p][0][o], -1.f), 1.f);
            w.y = fminf(fmaxf((float)acc[p][1][o], -1.f), 1.f);
            *(float2*)(out + ((gn * 2 + o) * 250 + (oy0 + p)) * 250 + 2 * ox) = w;
        }
}

extern "C" void kernel_launch(void* const* d_in, const int* in_sizes, int n_in,
                              void* d_out, int out_size, void* d_ws, size_t ws_size,
                              hipStream_t stream) {
    const float* x  = (const float*)d_in[0];
    const float* w1 = (const float*)d_in[1];
    const float* w2 = (const float*)d_in[2];
    const float* w3 = (const float*)d_in[3];
    const float* w4 = (const float*)d_in[4];
    char* ws = (char*)d_ws;

    int*   w2m = (int*)(ws + WOFF_W2M);
    int*   w3m = (int*)(ws + WOFF_W3M);
    int*   w4p = (int*)(ws + WOFF_W4P);
    f32x2* w1d = (f32x2*)(ws + WOFF_W1D);
    float* out = (float*)d_out;

    size_t per = (size_t)A1_PB + (size_t)A2_PB + (size_t)A3_PB;
    int NC = 32;
    while (NC > 1 && (size_t)WEIGHTS_BYTES + (size_t)NC * per > ws_size) NC >>= 1;

    uint32_t* A1 = (uint32_t*)(ws + WEIGHTS_BYTES);
    uint32_t* A2 = (uint32_t*)(ws + WEIGHTS_BYTES + (size_t)NC * A1_PB);
    uint32_t* A3 = (uint32_t*)(ws + WEIGHTS_BYTES + (size_t)NC * (A1_PB + A2_PB));

    kprep<<<dim3(3), 256, 0, stream>>>(w1, w2, w3, w4, w2m, w3m, w4p, w1d);
    for (int n0 = 0; n0 < 32; n0 += NC) {
        k1<<<dim3(1, 256, NC), 128, 0, stream>>>(x, w1d, A1, n0);
        kconv<2, 256, 254, 4><<<dim3(8, 32, NC), 256, 0, stream>>>(A1, w2m, A2);
        kconv<4, 254, 252, 8><<<dim3(8, 32, NC), 256, 0, stream>>>(A2, w3m, A3);
        k4<<<dim3(1, 125, NC), 128, 0, stream>>>(A3, w4p, out, n0);
    }
}

// Round 21
// 146.005 us; speedup vs baseline: 1.0307x; 1.0307x over previous
//
#include <hip/hip_runtime.h>
#include <hip/hip_bf16.h>
#include <cstdint>

// ---------------------------------------------------------------------------
// Binarized CNN. Verified numerics (R5-R20 passed bit-exact):
//  - binarize(x) == sign(x) exactly; layers 2-4 are exact small-int math in
//    any order -> any packing / instruction choice is safe.
//  - conv1: each accumulator chain MUST sum in (ky,kx,ic)-ascending order
//    (Eigen/XLA-CPU im2col). Chains independent; fma == mul+add (w in +-1/0).
//    DO NOT reorder WITHIN a chain. Pad value 1.0.
//  - k1: R20 2-cells/thread pk_fma (bit-exact contract; ~58us, near its
//    157TF-f32-pipe floor of ~23us x latency factor — frozen).
//  - k2: MFMA i32_32x32x32_i8 per-tap GEMM, weights-as-A (R18).
//  - R21: k3+k4 FUSED (kconv34): per block compute 50x8 final outputs;
//    A3 52x10 halo computed via MFMA into LDS (never hits global), then
//    3x3x32->2 dot4 phase reads LDS uint2 pairs. Removes A3 HBM round-trip
//    (~130MB) and the k4 dispatch.
// ---------------------------------------------------------------------------

typedef __attribute__((ext_vector_type(2)))  float f32x2;
typedef __attribute__((ext_vector_type(4)))  int int4v;
typedef __attribute__((ext_vector_type(16))) int int16v;

#define WOFF_W2M 0          // int[9*64*4] = 9216 B (MFMA frag table L2)
#define WOFF_W3M 10240      // int[9*64*4] = 9216 B (MFMA frag table L3)
#define WOFF_W4P 20480      // int[2*8*9]  =  576 B (dot4 packs L4)
#define WOFF_W1D 28672      // f32x2[4*32] = 1024 B (padded {w2o,w2o+1} pairs)
#define WEIGHTS_BYTES 32768

#define A1_PB (2*256*256*4)     // bytes per batch (packed u32, 4 ch/dword)
#define A2_PB (4*254*254*4)

__device__ __forceinline__ int dot4(int a, int b, int c) {
#if __has_builtin(__builtin_amdgcn_sdot4)
    return __builtin_amdgcn_sdot4(a, b, c, false);
#else
    int s = c;
#pragma unroll
    for (int j = 0; j < 4; ++j) {
        int av = (a << (24 - 8 * j)) >> 24;
        int bv = (b << (24 - 8 * j)) >> 24;
        s += av * bv;
    }
    return s;
#endif
}

__device__ __forceinline__ int fsign(float w) {
    return (w > 0.f) ? 1 : ((w < 0.f) ? -1 : 0);
}

// acc.lo += w.lo * v.lo ; acc.hi += w.hi * v.lo   (broadcast LOW of src1)
__device__ __forceinline__ void pkfma_lo(f32x2& acc, f32x2 w, f32x2 v) {
    asm("v_pk_fma_f32 %0, %1, %2, %0 op_sel:[0,0,0] op_sel_hi:[1,0,1]"
        : "+v"(acc) : "s"(w), "v"(v));
}
// acc.lo += w.lo * v.hi ; acc.hi += w.hi * v.hi   (broadcast HIGH of src1)
__device__ __forceinline__ void pkfma_hi(f32x2& acc, f32x2 w, f32x2 v) {
    asm("v_pk_fma_f32 %0, %1, %2, %0 op_sel:[0,1,0] op_sel_hi:[1,1,1]"
        : "+v"(acc) : "s"(w), "v"(v));
}

// ---- weight prep: 3 blocks (one per table group) -------------------------
__global__ __launch_bounds__(256) void kprep(const float* __restrict__ w1,
                                             const float* __restrict__ w2,
                                             const float* __restrict__ w3,
                                             const float* __restrict__ w4,
                                             int* __restrict__ w2m,
                                             int* __restrict__ w3m,
                                             int* __restrict__ w4p,
                                             f32x2* __restrict__ w1d) {
    int tid = threadIdx.x;
    int b = blockIdx.x;
    if (b == 0) {
        for (int idx = tid; idx < 576; idx += 256) {
            int t = idx / 64, l = idx % 64;
            int oc = l & 31, icb = (l >> 5) * 16;
            int wd[4] = {0, 0, 0, 0};
            for (int j = 0; j < 16; ++j) {
                int ic = icb + j;
                int s = (oc < 16 && ic < 8) ? fsign(w2[(oc * 8 + ic) * 9 + t]) : 0;
                wd[j >> 2] |= (s & 0xff) << (8 * (j & 3));
            }
            w2m[idx * 4 + 0] = wd[0]; w2m[idx * 4 + 1] = wd[1];
            w2m[idx * 4 + 2] = wd[2]; w2m[idx * 4 + 3] = wd[3];
        }
    } else if (b == 1) {
        for (int idx = tid; idx < 576; idx += 256) {
            int t = idx / 64, l = idx % 64;
            int oc = l & 31, icb = (l >> 5) * 16;
            int wd[4] = {0, 0, 0, 0};
            for (int j = 0; j < 16; ++j) {
                int ic = icb + j;
                int s = (ic < 16) ? fsign(w3[(oc * 16 + ic) * 9 + t]) : 0;
                wd[j >> 2] |= (s & 0xff) << (8 * (j & 3));
            }
            w3m[idx * 4 + 0] = wd[0]; w3m[idx * 4 + 1] = wd[1];
            w3m[idx * 4 + 2] = wd[2]; w3m[idx * 4 + 3] = wd[3];
        }
    } else {
        for (int idx = tid; idx < 2 * 8 * 9; idx += 256) {
            int k = idx % 9, icg = (idx / 9) % 8, oc = idx / 72;
            int pack = 0;
#pragma unroll
            for (int j = 0; j < 4; ++j)
                pack |= (fsign(w4[(oc * 32 + icg * 4 + j) * 9 + k]) & 0xff) << (8 * j);
            w4p[idx] = pack;
        }
        // padded table: w1d[op*32 + t] (t<27), 256B-aligned per op block
        for (int i = tid; i < 128; i += 256) {
            int op = i / 32, t = i % 32;
            f32x2 pr = {0.f, 0.f};
            if (t < 27) {
                float wa = w1[(2 * op) * 27 + t];
                float wbv = w1[(2 * op + 1) * 27 + t];
                pr[0] = (wa > 0.f) ? 1.f : ((wa < 0.f) ? -1.f : 0.f);
                pr[1] = (wbv > 0.f) ? 1.f : ((wbv < 0.f) ? -1.f : 0.f);
            }
            w1d[i] = pr;
        }
    }
}

// ---- layer 1: pad(1)+conv(3->8)+hardtanh+maxpool2+sign, packed out -------
// R20 (verified): 2 pool cells/thread, float4 window loads, oc-paired
// pk_fma. Chains strict (ky,kx,ic)-ascending per contract.
__global__ __launch_bounds__(128, 4) void k1(const float* __restrict__ x,
                                             const f32x2* __restrict__ w1d,
                                             uint32_t* __restrict__ a1, int n0) {
    int tx = threadIdx.x;   // 0..127
    int oy = blockIdx.y;    // 0..255
    int ln = blockIdx.z;
    const float* xn = x + (size_t)(n0 + ln) * 3 * 512 * 512;

    int iy0 = 2 * oy - 1;
    int xb  = 4 * tx;        // window cols xb-1 .. xb+4

    f32x2 P[3][4][3];        // [ic][r][pair]

    if (oy > 0 && oy < 255 && tx > 0 && tx < 127) {
#pragma unroll
        for (int ic = 0; ic < 3; ++ic) {
            const float* xc = xn + (size_t)ic * 512 * 512;
#pragma unroll
            for (int r = 0; r < 4; ++r) {
                const float* rp = xc + (size_t)(iy0 + r) * 512 + xb;
                float  lft = rp[-1];
                float4 m   = *(const float4*)rp;    // cols xb..xb+3, 16B aligned
                float  rgt = rp[4];
                P[ic][r][0] = (f32x2){lft, m.x};
                P[ic][r][1] = (f32x2){m.y, m.z};
                P[ic][r][2] = (f32x2){m.w, rgt};
            }
        }
    } else {
        for (int ic = 0; ic < 3; ++ic) {
            const float* xc = xn + (size_t)ic * 512 * 512;
#pragma unroll
            for (int r = 0; r < 4; ++r) {
                int iy = iy0 + r;
                bool yok = ((unsigned)iy < 512u);
                float t[6];
#pragma unroll
                for (int c = 0; c < 6; ++c) {
                    int ix = xb - 1 + c;
                    t[c] = (yok && ((unsigned)ix < 512u))
                               ? xc[(size_t)iy * 512 + ix] : 1.0f;
                }
                P[ic][r][0] = (f32x2){t[0], t[1]};
                P[ic][r][1] = (f32x2){t[2], t[3]};
                P[ic][r][2] = (f32x2){t[4], t[5]};
            }
        }
    }

#define PKTAP(ACC, ROW, COL)                                         \
    do {                                                             \
        if (((COL) & 1) == 0) pkfma_lo(ACC, ww, P[ic][ROW][(COL) >> 1]); \
        else                  pkfma_hi(ACC, ww, P[ic][ROW][(COL) >> 1]); \
    } while (0)

    uint64_t dallA = 0, dallB = 0;
#pragma unroll 1
    for (int op = 0; op < 4; ++op) {
        const f32x2* wb = w1d + op * 32;
        f32x2 wop[27];
#pragma unroll
        for (int t = 0; t < 27; ++t) wop[t] = wb[t];

        f32x2 aA00 = {0.f, 0.f}, aA01 = {0.f, 0.f};
        f32x2 aA10 = {0.f, 0.f}, aA11 = {0.f, 0.f};
        f32x2 aB00 = {0.f, 0.f}, aB01 = {0.f, 0.f};
        f32x2 aB10 = {0.f, 0.f}, aB11 = {0.f, 0.f};
#pragma unroll
        for (int ky = 0; ky < 3; ++ky) {
#pragma unroll
            for (int kx = 0; kx < 3; ++kx) {
#pragma unroll
                for (int ic = 0; ic < 3; ++ic) {
                    f32x2 ww = wop[ic * 9 + ky * 3 + kx];
                    PKTAP(aA00, ky + 0, kx + 0);
                    PKTAP(aA01, ky + 0, kx + 1);
                    PKTAP(aA10, ky + 1, kx + 0);
                    PKTAP(aA11, ky + 1, kx + 1);
                    PKTAP(aB00, ky + 0, kx + 2);
                    PKTAP(aB01, ky + 0, kx + 3);
                    PKTAP(aB10, ky + 1, kx + 2);
                    PKTAP(aB11, ky + 1, kx + 3);
                }
            }
        }
        float mA0 = fmaxf(fmaxf(aA00[0], aA01[0]), fmaxf(aA10[0], aA11[0]));
        float mA1 = fmaxf(fmaxf(aA00[1], aA01[1]), fmaxf(aA10[1], aA11[1]));
        float mB0 = fmaxf(fmaxf(aB00[0], aB01[0]), fmaxf(aB10[0], aB11[0]));
        float mB1 = fmaxf(fmaxf(aB00[1], aB01[1]), fmaxf(aB10[1], aB11[1]));
        int sA0 = (mA0 > 0.f) ? 1 : ((mA0 < 0.f) ? -1 : 0);
        int sA1 = (mA1 > 0.f) ? 1 : ((mA1 < 0.f) ? -1 : 0);
        int sB0 = (mB0 > 0.f) ? 1 : ((mB0 < 0.f) ? -1 : 0);
        int sB1 = (mB1 > 0.f) ? 1 : ((mB1 < 0.f) ? -1 : 0);
        dallA |= (uint64_t)(uint32_t)(sA0 & 0xff) << (8 * (2 * op));
        dallA |= (uint64_t)(uint32_t)(sA1 & 0xff) << (8 * (2 * op + 1));
        dallB |= (uint64_t)(uint32_t)(sB0 & 0xff) << (8 * (2 * op));
        dallB |= (uint64_t)(uint32_t)(sB1 & 0xff) << (8 * (2 * op + 1));
    }
#undef PKTAP

    size_t base = (((size_t)ln * 2) * 256 + oy) * 256 + 2 * tx;
    uint2 v0, v1;
    v0.x = (uint32_t)dallA;         v0.y = (uint32_t)dallB;
    v1.x = (uint32_t)(dallA >> 32); v1.y = (uint32_t)(dallB >> 32);
    *(uint2*)(a1 + base)             = v0;
    *(uint2*)(a1 + base + 256 * 256) = v1;
}

// ---- layer 2: conv(8->16) ternary via MFMA (R16/R18 structure) -----------
__global__ __launch_bounds__(256) void kconv2(const uint32_t* __restrict__ ain,
                                              const int* __restrict__ wm,
                                              uint32_t* __restrict__ aout) {
    __shared__ uint32_t stb[10][36][2];    // [row][x][icg], ICG=2
    int w    = threadIdx.x >> 6;
    int lane = threadIdx.x & 63;
    int x0 = blockIdx.x * 32;
    int y0 = blockIdx.y * 8;
    int ln = blockIdx.z;

    const int4v* wmv = (const int4v*)wm;
    int4v bfr[9];
#pragma unroll
    for (int t = 0; t < 9; ++t) bfr[t] = wmv[t * 64 + lane];

    const uint32_t* abase = ain + (size_t)ln * 2 * 256 * 256;
    for (int idx = threadIdx.x; idx < 10 * 36 * 2; idx += 256) {
        int icg = idx & 1;
        int r2 = idx >> 1;
        int xx = r2 % 36, row = r2 / 36;
        int gy = y0 + row, gx = x0 + xx;
        uint32_t val = 0;
        if (xx < 34 && gx < 256 && gy < 256)
            val = abase[((size_t)icg * 256 + gy) * 256 + gx];
        stb[row][xx][icg] = val;
    }
    __syncthreads();

    int xl = lane & 31;
    int h  = lane >> 5;

#pragma unroll
    for (int ry = 0; ry < 2; ++ry) {
        int yy = y0 + 2 * w + ry;
        int16v acc = {};
#pragma unroll
        for (int ky = 0; ky < 3; ++ky) {
#pragma unroll
            for (int kx = 0; kx < 3; ++kx) {
                // A-fragment: 16 K-bytes = icg 0..3; icg>=2 garbage hits
                // zero B-bytes -> 0. Read 8B real + treat rest via same vec.
                uint32_t d0 = stb[2 * w + ry + ky][xl + kx][0];
                uint32_t d1 = stb[2 * w + ry + ky][xl + kx][1];
                int4v a; a[0] = (int)d0; a[1] = (int)d1; a[2] = 0; a[3] = 0;
                acc = __builtin_amdgcn_mfma_i32_32x32x32_i8(bfr[ky * 3 + kx], a, acc, 0, 0, 0);
            }
        }
        bool ok = (yy < 254) && (x0 + xl < 254);
#pragma unroll
        for (int g = 0; g < 4; ++g) {
            int ocg = 2 * g + h;              // oc = 8g + 4h + j, byte j
            if (ocg < 4 && ok) {
                uint32_t dw = 0;
#pragma unroll
                for (int j = 0; j < 4; ++j) {
                    int v = min(max(acc[4 * g + j], -1), 1);
                    dw |= (uint32_t)(v & 0xff) << (8 * j);
                }
                aout[(((size_t)ln * 4 + ocg) * 254 + yy) * 254 + x0 + xl] = dw;
            }
        }
    }
}

// ---- layers 3+4 fused: conv(16->32)+conv(32->2), out f32 -----------------
// Per block: 50x8 tile of final output. A3 halo (52x10, 2 MFMA col-tiles x
// 10 rows) computed into LDS, never written to global. Then 3x3x32->2 dot4.
__global__ __launch_bounds__(256) void kconv34(const uint32_t* __restrict__ a2,
                                               const int* __restrict__ w3m,
                                               const int* __restrict__ w4p,
                                               float* __restrict__ out, int n0) {
    __shared__ uint32_t sA2[12][68][4];    // rows y0..y0+11, cols x0..x0+65
    __shared__ uint32_t sA3[10][8][64];    // [row][ocg][col]
    int w    = threadIdx.x >> 6;
    int lane = threadIdx.x & 63;
    int x0 = blockIdx.x * 50;              // out col base: 0,50,100,150,200
    int y0 = blockIdx.y * 8;               // out row base: 0..248
    int ln = blockIdx.z;

    const int4v* wmv = (const int4v*)w3m;
    int4v bfr[9];
#pragma unroll
    for (int t = 0; t < 9; ++t) bfr[t] = wmv[t * 64 + lane];

    // stage A2 rows y0..y0+11, cols x0..x0+65 (guard 254)
    const uint32_t* abase = a2 + (size_t)ln * 4 * 254 * 254;
    for (int idx = threadIdx.x; idx < 12 * 66 * 4; idx += 256) {
        int icg = idx & 3;
        int r2 = idx >> 2;
        int xx = r2 % 66, row = r2 / 66;
        int gy = y0 + row, gx = x0 + xx;
        uint32_t val = 0;
        if (gy < 254 && gx < 254)
            val = abase[((size_t)icg * 254 + gy) * 254 + gx];
        sA2[row][xx][icg] = val;
    }
    __syncthreads();

    // compute A3 tile: 20 tile-rows (2 col-tiles x 10 rows), 5 per wave
    int xl = lane & 31;
    int h  = lane >> 5;
#pragma unroll
    for (int t5 = 0; t5 < 5; ++t5) {
        int t = w * 5 + t5;
        int ct = t / 10, row = t % 10;
        int16v acc = {};
#pragma unroll
        for (int ky = 0; ky < 3; ++ky) {
#pragma unroll
            for (int kx = 0; kx < 3; ++kx) {
                int4v a = *(const int4v*)&sA2[row + ky][ct * 32 + xl + kx][0];
                acc = __builtin_amdgcn_mfma_i32_32x32x32_i8(bfr[ky * 3 + kx], a, acc, 0, 0, 0);
            }
        }
#pragma unroll
        for (int g = 0; g < 4; ++g) {
            uint32_t dw = 0;
#pragma unroll
            for (int j = 0; j < 4; ++j) {
                int v = min(max(acc[4 * g + j], -1), 1);
                dw |= (uint32_t)(v & 0xff) << (8 * j);
            }
            sA3[row][2 * g + h][ct * 32 + xl] = dw;
        }
    }
    __syncthreads();

    // k4 phase: 8 rows x 50 cols; threads handle 2-wide pairs (x even)
    size_t gn = (size_t)(n0 + ln);
    int o = threadIdx.x;
    if (o < 200) {
        int y  = o / 25;
        int xp = (o % 25) * 2;             // local out cols xp, xp+1
        int gy = y0 + y;
        if (gy < 250) {
            int acc00 = 0, acc01 = 0, acc10 = 0, acc11 = 0;  // [outAB][oc]
#pragma unroll
            for (int icg = 0; icg < 8; ++icg) {
#pragma unroll
                for (int ky = 0; ky < 3; ++ky) {
                    uint2 lo = *(const uint2*)&sA3[y + ky][icg][xp];
                    uint2 hi = *(const uint2*)&sA3[y + ky][icg][xp + 2];
                    int c0 = (int)lo.x, c1 = (int)lo.y, c2 = (int)hi.x, c3 = (int)hi.y;
                    const int* wb0 = w4p + (0 * 8 + icg) * 9 + ky * 3;
                    const int* wb1 = w4p + (1 * 8 + icg) * 9 + ky * 3;
                    acc00 = dot4(c0, wb0[0], acc00);
                    acc00 = dot4(c1, wb0[1], acc00);
                    acc00 = dot4(c2, wb0[2], acc00);
                    acc01 = dot4(c0, wb1[0], acc01);
                    acc01 = dot4(c1, wb1[1], acc01);
                    acc01 = dot4(c2, wb1[2], acc01);
                    acc10 = dot4(c1, wb0[0], acc10);
                    acc10 = dot4(c2, wb0[1], acc10);
                    acc10 = dot4(c3, wb0[2], acc10);
                    acc11 = dot4(c1, wb1[0], acc11);
                    acc11 = dot4(c2, wb1[1], acc11);
                    acc11 = dot4(c3, wb1[2], acc11);
                }
            }
            float2 o0, o1;
            o0.x = fminf(fmaxf((float)acc00, -1.f), 1.f);
            o0.y = fminf(fmaxf((float)acc10, -1.f), 1.f);
            o1.x = fminf(fmaxf((float)acc01, -1.f), 1.f);
            o1.y = fminf(fmaxf((float)acc11, -1.f), 1.f);
            *(float2*)(out + ((gn * 2 + 0) * 250 + gy) * 250 + x0 + xp) = o0;
            *(float2*)(out + ((gn * 2 + 1) * 250 + gy) * 250 + x0 + xp) = o1;
        }
    }
}

extern "C" void kernel_launch(void* const* d_in, const int* in_sizes, int n_in,
                              void* d_out, int out_size, void* d_ws, size_t ws_size,
                              hipStream_t stream) {
    const float* x  = (const float*)d_in[0];
    const float* w1 = (const float*)d_in[1];
    const float* w2 = (const float*)d_in[2];
    const float* w3 = (const float*)d_in[3];
    const float* w4 = (const float*)d_in[4];
    char* ws = (char*)d_ws;

    int*   w2m = (int*)(ws + WOFF_W2M);
    int*   w3m = (int*)(ws + WOFF_W3M);
    int*   w4p = (int*)(ws + WOFF_W4P);
    f32x2* w1d = (f32x2*)(ws + WOFF_W1D);
    float* out = (float*)d_out;

    size_t per = (size_t)A1_PB + (size_t)A2_PB;   // A3 no longer materialized
    int NC = 32;
    while (NC > 1 && (size_t)WEIGHTS_BYTES + (size_t)NC * per > ws_size) NC >>= 1;

    uint32_t* A1 = (uint32_t*)(ws + WEIGHTS_BYTES);
    uint32_t* A2 = (uint32_t*)(ws + WEIGHTS_BYTES + (size_t)NC * A1_PB);

    kprep<<<dim3(3), 256, 0, stream>>>(w1, w2, w3, w4, w2m, w3m, w4p, w1d);
    for (int n0 = 0; n0 < 32; n0 += NC) {
        k1<<<dim3(1, 256, NC), 128, 0, stream>>>(x, w1d, A1, n0);
        kconv2<<<dim3(8, 32, NC), 256, 0, stream>>>(A1, w2m, A2);
        kconv34<<<dim3(5, 32, NC), 256, 0, stream>>>(A2, w3m, w4p, out, n0);
    }
}

// Round 22
// 140.510 us; speedup vs baseline: 1.0710x; 1.0391x over previous
//
#include <hip/hip_runtime.h>
#include <hip/hip_bf16.h>
#include <cstdint>

// ---------------------------------------------------------------------------
// Binarized CNN. Verified numerics (R5-R21 passed bit-exact):
//  - binarize(x) == sign(x) exactly; layers 2-4 are exact small-int math in
//    any order -> any packing / instruction choice is safe.
//  - conv1: each accumulator chain MUST sum in (ky,kx,ic)-ascending order
//    (Eigen/XLA-CPU im2col). Chains independent; fma == mul+add (w in +-1/0).
//    DO NOT reorder WITHIN a chain. Pad value 1.0.
//  - k1: R20 2-cells/thread pk_fma (frozen, ~58us).
//  - k2: MFMA i32_32x32x32_i8 per-tap GEMM, weights-as-A (R18).
//  - R22: kconv34 phase-2 (the 3x3x32->2 conv) now MFMA too — "dot4" is
//    suspected to be a 12-op fallback on gfx950 (R21: 42us VALU-busy far
//    exceeds single-instr dot4 count). w4m table (R13-verified) as A operand
//    (R18-verified swap) -> C[oc,px]; A3 in LDS pixel-major with 9-dword
//    pixel stride (9 coprime 32 -> conflict-free both phases). All indexing
//    pow2; tile 62 cols = exactly 2 MFMA col-tiles; no dot4 anywhere.
// ---------------------------------------------------------------------------

typedef __attribute__((ext_vector_type(2)))  float f32x2;
typedef __attribute__((ext_vector_type(4)))  int int4v;
typedef __attribute__((ext_vector_type(16))) int int16v;

#define WOFF_W2M 0          // int[9*64*4] = 9216 B (MFMA frag table L2)
#define WOFF_W3M 10240      // int[9*64*4] = 9216 B (MFMA frag table L3)
#define WOFF_W4M 20480      // int[9*64*4] = 9216 B (MFMA frag table L4, K=32)
#define WOFF_W1D 30720      // f32x2[4*32] = 1024 B (padded {w2o,w2o+1} pairs)
#define WEIGHTS_BYTES 32768

#define A1_PB (2*256*256*4)     // bytes per batch (packed u32, 4 ch/dword)
#define A2_PB (4*254*254*4)

__device__ __forceinline__ int fsign(float w) {
    return (w > 0.f) ? 1 : ((w < 0.f) ? -1 : 0);
}

// acc.lo += w.lo * v.lo ; acc.hi += w.hi * v.lo   (broadcast LOW of src1)
__device__ __forceinline__ void pkfma_lo(f32x2& acc, f32x2 w, f32x2 v) {
    asm("v_pk_fma_f32 %0, %1, %2, %0 op_sel:[0,0,0] op_sel_hi:[1,0,1]"
        : "+v"(acc) : "s"(w), "v"(v));
}
// acc.lo += w.lo * v.hi ; acc.hi += w.hi * v.hi   (broadcast HIGH of src1)
__device__ __forceinline__ void pkfma_hi(f32x2& acc, f32x2 w, f32x2 v) {
    asm("v_pk_fma_f32 %0, %1, %2, %0 op_sel:[0,1,0] op_sel_hi:[1,1,1]"
        : "+v"(acc) : "s"(w), "v"(v));
}

// ---- weight prep: 3 blocks (one per table group) -------------------------
__global__ __launch_bounds__(256) void kprep(const float* __restrict__ w1,
                                             const float* __restrict__ w2,
                                             const float* __restrict__ w3,
                                             const float* __restrict__ w4,
                                             int* __restrict__ w2m,
                                             int* __restrict__ w3m,
                                             int* __restrict__ w4m,
                                             f32x2* __restrict__ w1d) {
    int tid = threadIdx.x;
    int b = blockIdx.x;
    if (b == 0) {
        for (int idx = tid; idx < 576; idx += 256) {
            int t = idx / 64, l = idx % 64;
            int oc = l & 31, icb = (l >> 5) * 16;
            int wd[4] = {0, 0, 0, 0};
            for (int j = 0; j < 16; ++j) {
                int ic = icb + j;
                int s = (oc < 16 && ic < 8) ? fsign(w2[(oc * 8 + ic) * 9 + t]) : 0;
                wd[j >> 2] |= (s & 0xff) << (8 * (j & 3));
            }
            w2m[idx * 4 + 0] = wd[0]; w2m[idx * 4 + 1] = wd[1];
            w2m[idx * 4 + 2] = wd[2]; w2m[idx * 4 + 3] = wd[3];
        }
    } else if (b == 1) {
        for (int idx = tid; idx < 576; idx += 256) {
            int t = idx / 64, l = idx % 64;
            int oc = l & 31, icb = (l >> 5) * 16;
            int wd[4] = {0, 0, 0, 0};
            for (int j = 0; j < 16; ++j) {
                int ic = icb + j;
                int s = (ic < 16) ? fsign(w3[(oc * 16 + ic) * 9 + t]) : 0;
                wd[j >> 2] |= (s & 0xff) << (8 * (j & 3));
            }
            w3m[idx * 4 + 0] = wd[0]; w3m[idx * 4 + 1] = wd[1];
            w3m[idx * 4 + 2] = wd[2]; w3m[idx * 4 + 3] = wd[3];
        }
    } else {
        // L4 MFMA table: K=32 all real, only oc 0,1 nonzero (R13-verified)
        for (int idx = tid; idx < 576; idx += 256) {
            int t = idx / 64, l = idx % 64;
            int oc = l & 31, icb = (l >> 5) * 16;
            int wd[4] = {0, 0, 0, 0};
            for (int j = 0; j < 16; ++j) {
                int ic = icb + j;
                int s = (oc < 2) ? fsign(w4[(oc * 32 + ic) * 9 + t]) : 0;
                wd[j >> 2] |= (s & 0xff) << (8 * (j & 3));
            }
            w4m[idx * 4 + 0] = wd[0]; w4m[idx * 4 + 1] = wd[1];
            w4m[idx * 4 + 2] = wd[2]; w4m[idx * 4 + 3] = wd[3];
        }
        // padded table: w1d[op*32 + t] (t<27), 256B-aligned per op block
        for (int i = tid; i < 128; i += 256) {
            int op = i / 32, t = i % 32;
            f32x2 pr = {0.f, 0.f};
            if (t < 27) {
                float wa = w1[(2 * op) * 27 + t];
                float wbv = w1[(2 * op + 1) * 27 + t];
                pr[0] = (wa > 0.f) ? 1.f : ((wa < 0.f) ? -1.f : 0.f);
                pr[1] = (wbv > 0.f) ? 1.f : ((wbv < 0.f) ? -1.f : 0.f);
            }
            w1d[i] = pr;
        }
    }
}

// ---- layer 1: pad(1)+conv(3->8)+hardtanh+maxpool2+sign, packed out -------
// R20 (verified): 2 pool cells/thread, float4 window loads, oc-paired
// pk_fma. Chains strict (ky,kx,ic)-ascending per contract.
__global__ __launch_bounds__(128, 4) void k1(const float* __restrict__ x,
                                             const f32x2* __restrict__ w1d,
                                             uint32_t* __restrict__ a1, int n0) {
    int tx = threadIdx.x;   // 0..127
    int oy = blockIdx.y;    // 0..255
    int ln = blockIdx.z;
    const float* xn = x + (size_t)(n0 + ln) * 3 * 512 * 512;

    int iy0 = 2 * oy - 1;
    int xb  = 4 * tx;        // window cols xb-1 .. xb+4

    f32x2 P[3][4][3];        // [ic][r][pair]

    if (oy > 0 && oy < 255 && tx > 0 && tx < 127) {
#pragma unroll
        for (int ic = 0; ic < 3; ++ic) {
            const float* xc = xn + (size_t)ic * 512 * 512;
#pragma unroll
            for (int r = 0; r < 4; ++r) {
                const float* rp = xc + (size_t)(iy0 + r) * 512 + xb;
                float  lft = rp[-1];
                float4 m   = *(const float4*)rp;    // cols xb..xb+3, 16B aligned
                float  rgt = rp[4];
                P[ic][r][0] = (f32x2){lft, m.x};
                P[ic][r][1] = (f32x2){m.y, m.z};
                P[ic][r][2] = (f32x2){m.w, rgt};
            }
        }
    } else {
        for (int ic = 0; ic < 3; ++ic) {
            const float* xc = xn + (size_t)ic * 512 * 512;
#pragma unroll
            for (int r = 0; r < 4; ++r) {
                int iy = iy0 + r;
                bool yok = ((unsigned)iy < 512u);
                float t[6];
#pragma unroll
                for (int c = 0; c < 6; ++c) {
                    int ix = xb - 1 + c;
                    t[c] = (yok && ((unsigned)ix < 512u))
                               ? xc[(size_t)iy * 512 + ix] : 1.0f;
                }
                P[ic][r][0] = (f32x2){t[0], t[1]};
                P[ic][r][1] = (f32x2){t[2], t[3]};
                P[ic][r][2] = (f32x2){t[4], t[5]};
            }
        }
    }

#define PKTAP(ACC, ROW, COL)                                         \
    do {                                                             \
        if (((COL) & 1) == 0) pkfma_lo(ACC, ww, P[ic][ROW][(COL) >> 1]); \
        else                  pkfma_hi(ACC, ww, P[ic][ROW][(COL) >> 1]); \
    } while (0)

    uint64_t dallA = 0, dallB = 0;
#pragma unroll 1
    for (int op = 0; op < 4; ++op) {
        const f32x2* wb = w1d + op * 32;
        f32x2 wop[27];
#pragma unroll
        for (int t = 0; t < 27; ++t) wop[t] = wb[t];

        f32x2 aA00 = {0.f, 0.f}, aA01 = {0.f, 0.f};
        f32x2 aA10 = {0.f, 0.f}, aA11 = {0.f, 0.f};
        f32x2 aB00 = {0.f, 0.f}, aB01 = {0.f, 0.f};
        f32x2 aB10 = {0.f, 0.f}, aB11 = {0.f, 0.f};
#pragma unroll
        for (int ky = 0; ky < 3; ++ky) {
#pragma unroll
            for (int kx = 0; kx < 3; ++kx) {
#pragma unroll
                for (int ic = 0; ic < 3; ++ic) {
                    f32x2 ww = wop[ic * 9 + ky * 3 + kx];
                    PKTAP(aA00, ky + 0, kx + 0);
                    PKTAP(aA01, ky + 0, kx + 1);
                    PKTAP(aA10, ky + 1, kx + 0);
                    PKTAP(aA11, ky + 1, kx + 1);
                    PKTAP(aB00, ky + 0, kx + 2);
                    PKTAP(aB01, ky + 0, kx + 3);
                    PKTAP(aB10, ky + 1, kx + 2);
                    PKTAP(aB11, ky + 1, kx + 3);
                }
            }
        }
        float mA0 = fmaxf(fmaxf(aA00[0], aA01[0]), fmaxf(aA10[0], aA11[0]));
        float mA1 = fmaxf(fmaxf(aA00[1], aA01[1]), fmaxf(aA10[1], aA11[1]));
        float mB0 = fmaxf(fmaxf(aB00[0], aB01[0]), fmaxf(aB10[0], aB11[0]));
        float mB1 = fmaxf(fmaxf(aB00[1], aB01[1]), fmaxf(aB10[1], aB11[1]));
        int sA0 = (mA0 > 0.f) ? 1 : ((mA0 < 0.f) ? -1 : 0);
        int sA1 = (mA1 > 0.f) ? 1 : ((mA1 < 0.f) ? -1 : 0);
        int sB0 = (mB0 > 0.f) ? 1 : ((mB0 < 0.f) ? -1 : 0);
        int sB1 = (mB1 > 0.f) ? 1 : ((mB1 < 0.f) ? -1 : 0);
        dallA |= (uint64_t)(uint32_t)(sA0 & 0xff) << (8 * (2 * op));
        dallA |= (uint64_t)(uint32_t)(sA1 & 0xff) << (8 * (2 * op + 1));
        dallB |= (uint64_t)(uint32_t)(sB0 & 0xff) << (8 * (2 * op));
        dallB |= (uint64_t)(uint32_t)(sB1 & 0xff) << (8 * (2 * op + 1));
    }
#undef PKTAP

    size_t base = (((size_t)ln * 2) * 256 + oy) * 256 + 2 * tx;
    uint2 v0, v1;
    v0.x = (uint32_t)dallA;         v0.y = (uint32_t)dallB;
    v1.x = (uint32_t)(dallA >> 32); v1.y = (uint32_t)(dallB >> 32);
    *(uint2*)(a1 + base)             = v0;
    *(uint2*)(a1 + base + 256 * 256) = v1;
}

// ---- layer 2: conv(8->16) ternary via MFMA (R18/R21, verified) -----------
__global__ __launch_bounds__(256) void kconv2(const uint32_t* __restrict__ ain,
                                              const int* __restrict__ wm,
                                              uint32_t* __restrict__ aout) {
    __shared__ uint32_t stb[10][36][2];    // [row][x][icg], ICG=2
    int w    = threadIdx.x >> 6;
    int lane = threadIdx.x & 63;
    int x0 = blockIdx.x * 32;
    int y0 = blockIdx.y * 8;
    int ln = blockIdx.z;

    const int4v* wmv = (const int4v*)wm;
    int4v bfr[9];
#pragma unroll
    for (int t = 0; t < 9; ++t) bfr[t] = wmv[t * 64 + lane];

    const uint32_t* abase = ain + (size_t)ln * 2 * 256 * 256;
    for (int idx = threadIdx.x; idx < 10 * 36 * 2; idx += 256) {
        int icg = idx & 1;
        int r2 = idx >> 1;
        int xx = r2 % 36, row = r2 / 36;
        int gy = y0 + row, gx = x0 + xx;
        uint32_t val = 0;
        if (xx < 34 && gx < 256 && gy < 256)
            val = abase[((size_t)icg * 256 + gy) * 256 + gx];
        stb[row][xx][icg] = val;
    }
    __syncthreads();

    int xl = lane & 31;
    int h  = lane >> 5;

#pragma unroll
    for (int ry = 0; ry < 2; ++ry) {
        int yy = y0 + 2 * w + ry;
        int16v acc = {};
#pragma unroll
        for (int ky = 0; ky < 3; ++ky) {
#pragma unroll
            for (int kx = 0; kx < 3; ++kx) {
                uint32_t d0 = stb[2 * w + ry + ky][xl + kx][0];
                uint32_t d1 = stb[2 * w + ry + ky][xl + kx][1];
                int4v a; a[0] = (int)d0; a[1] = (int)d1; a[2] = 0; a[3] = 0;
                acc = __builtin_amdgcn_mfma_i32_32x32x32_i8(bfr[ky * 3 + kx], a, acc, 0, 0, 0);
            }
        }
        bool ok = (yy < 254) && (x0 + xl < 254);
#pragma unroll
        for (int g = 0; g < 4; ++g) {
            int ocg = 2 * g + h;
            if (ocg < 4 && ok) {
                uint32_t dw = 0;
#pragma unroll
                for (int j = 0; j < 4; ++j) {
                    int v = min(max(acc[4 * g + j], -1), 1);
                    dw |= (uint32_t)(v & 0xff) << (8 * j);
                }
                aout[(((size_t)ln * 4 + ocg) * 254 + yy) * 254 + x0 + xl] = dw;
            }
        }
    }
}

// ---- layers 3+4 fused, all-MFMA: conv(16->32)+conv(32->2), f32 out -------
// Tile: 62x8 final outputs; A3 halo 64x10 in LDS pixel-major, 9-dword
// pixel stride (9 coprime 32 -> conflict-free writes and reads).
__global__ __launch_bounds__(256) void kconv34(const uint32_t* __restrict__ a2,
                                               const int* __restrict__ w3m,
                                               const int* __restrict__ w4m,
                                               float* __restrict__ out, int n0) {
    __shared__ uint32_t sA2[12][68][4];      // rows y0..y0+11, cols x0..x0+65
    __shared__ uint32_t sA3[10 * 66 * 9];    // [row][px(66)][icg-dword(9 pad)]
    int w    = threadIdx.x >> 6;
    int lane = threadIdx.x & 63;
    int xl = lane & 31;
    int h  = lane >> 5;
    int x0 = blockIdx.x * 62;                // out col base
    int y0 = blockIdx.y * 8;                 // out row base
    int ln = blockIdx.z;

    const int4v* wmv3 = (const int4v*)w3m;
    int4v bfr[9];
#pragma unroll
    for (int t = 0; t < 9; ++t) bfr[t] = wmv3[t * 64 + lane];

    // stage A2 rows y0..y0+11, cols x0..x0+65 (guard 254); pow2 indexing
    const uint32_t* abase = a2 + (size_t)ln * 4 * 254 * 254;
    for (int idx = threadIdx.x; idx < 12 * 64 * 4; idx += 256) {
        int row = idx >> 8;                  // 0..11
        int xx  = (idx >> 2) & 63;           // 0..63
        int icg = idx & 3;
        int gy = y0 + row, gx = x0 + xx;
        uint32_t val = 0;
        if (gy < 254 && gx < 254)
            val = abase[((size_t)icg * 254 + gy) * 254 + gx];
        sA2[row][xx][icg] = val;
    }
    if (threadIdx.x < 96) {                  // tail cols 64,65
        int row = threadIdx.x >> 3;
        int xx  = 64 + ((threadIdx.x >> 2) & 1);
        int icg = threadIdx.x & 3;
        int gy = y0 + row, gx = x0 + xx;
        uint32_t val = 0;
        if (gy < 254 && gx < 254)
            val = abase[((size_t)icg * 254 + gy) * 254 + gx];
        sA2[row][xx][icg] = val;
    }
    __syncthreads();

    // phase 1: A3 tile (10 rows x 64 cols) via MFMA, 20 tiles, 5/wave
#pragma unroll
    for (int t5 = 0; t5 < 5; ++t5) {
        int t = t5 * 4 + w;                  // 0..19
        int row = t >> 1, ct = t & 1;
        int16v acc = {};
#pragma unroll
        for (int ky = 0; ky < 3; ++ky) {
#pragma unroll
            for (int kx = 0; kx < 3; ++kx) {
                int4v a = *(const int4v*)&sA2[row + ky][ct * 32 + xl + kx][0];
                acc = __builtin_amdgcn_mfma_i32_32x32x32_i8(bfr[ky * 3 + kx], a, acc, 0, 0, 0);
            }
        }
        int pbase = (row * 66 + ct * 32 + xl) * 9;
#pragma unroll
        for (int g = 0; g < 4; ++g) {
            uint32_t dw = 0;
#pragma unroll
            for (int j = 0; j < 4; ++j) {
                int v = min(max(acc[4 * g + j], -1), 1);
                dw |= (uint32_t)(v & 0xff) << (8 * j);
            }
            sA3[pbase + 2 * g + h] = dw;
        }
    }

    // load L4 A-frags (w3m bfr dead after this point; regs reusable)
    const int4v* wmv4 = (const int4v*)w4m;
    int4v bf4[9];
#pragma unroll
    for (int t = 0; t < 9; ++t) bf4[t] = wmv4[t * 64 + lane];
    __syncthreads();

    // phase 2: 3x3x32->2 conv via MFMA; 16 tiles (8 rows x 2 col-tiles)
    size_t gn = (size_t)(n0 + ln);
#pragma unroll
    for (int t4 = 0; t4 < 4; ++t4) {
        int t = t4 * 4 + w;                  // 0..15
        int y = t >> 1, ct2 = t & 1;
        int gy = y0 + y;
        int16v acc = {};
#pragma unroll
        for (int ky = 0; ky < 3; ++ky) {
#pragma unroll
            for (int kx = 0; kx < 3; ++kx) {
                const uint32_t* pb = &sA3[((y + ky) * 66 + ct2 * 32 + xl + kx) * 9 + h * 4];
                int4v bv;
                bv[0] = (int)pb[0]; bv[1] = (int)pb[1];
                bv[2] = (int)pb[2]; bv[3] = (int)pb[3];
                acc = __builtin_amdgcn_mfma_i32_32x32x32_i8(bf4[ky * 3 + kx], bv, acc, 0, 0, 0);
            }
        }
        // C[row=oc, col=px]: oc 0 -> reg 0, oc 1 -> reg 1, lanes h==0
        if (h == 0) {
            int lx = ct2 * 32 + xl;
            if (lx < 62 && x0 + lx < 250 && gy < 250) {
                float v0 = fminf(fmaxf((float)acc[0], -1.f), 1.f);
                float v1 = fminf(fmaxf((float)acc[1], -1.f), 1.f);
                out[((gn * 2 + 0) * 250 + gy) * 250 + x0 + lx] = v0;
                out[((gn * 2 + 1) * 250 + gy) * 250 + x0 + lx] = v1;
            }
        }
    }
}

extern "C" void kernel_launch(void* const* d_in, const int* in_sizes, int n_in,
                              void* d_out, int out_size, void* d_ws, size_t ws_size,
                              hipStream_t stream) {
    const float* x  = (const float*)d_in[0];
    const float* w1 = (const float*)d_in[1];
    const float* w2 = (const float*)d_in[2];
    const float* w3 = (const float*)d_in[3];
    const float* w4 = (const float*)d_in[4];
    char* ws = (char*)d_ws;

    int*   w2m = (int*)(ws + WOFF_W2M);
    int*   w3m = (int*)(ws + WOFF_W3M);
    int*   w4m = (int*)(ws + WOFF_W4M);
    f32x2* w1d = (f32x2*)(ws + WOFF_W1D);
    float* out = (float*)d_out;

    size_t per = (size_t)A1_PB + (size_t)A2_PB;   // A3 never materialized
    int NC = 32;
    while (NC > 1 && (size_t)WEIGHTS_BYTES + (size_t)NC * per > ws_size) NC >>= 1;

    uint32_t* A1 = (uint32_t*)(ws + WEIGHTS_BYTES);
    uint32_t* A2 = (uint32_t*)(ws + WEIGHTS_BYTES + (size_t)NC * A1_PB);

    kprep<<<dim3(3), 256, 0, stream>>>(w1, w2, w3, w4, w2m, w3m, w4m, w1d);
    for (int n0 = 0; n0 < 32; n0 += NC) {
        k1<<<dim3(1, 256, NC), 128, 0, stream>>>(x, w1d, A1, n0);
        kconv2<<<dim3(8, 32, NC), 256, 0, stream>>>(A1, w2m, A2);
        kconv34<<<dim3(5, 32, NC), 256, 0, stream>>>(A2, w3m, w4m, out, n0);
    }
}